// Round 1
// baseline (265.992 us; speedup 1.0000x reference)
//
#include <hip/hip_runtime.h>
#include <hip/hip_bf16.h>
#include <math.h>

#define N_NODES 50000
#define DIN     128
#define DOUT    128
#define EPS_    1e-6f
#define NBKT    196          // coarse buckets: dst>>8 (256 nodes each)
#define EPB     4096         // edges per histogram block
#define NB_PROJ 782          // ceil(3125/4) proj blocks

typedef __attribute__((ext_vector_type(8))) short  bf16x8;
typedef __attribute__((ext_vector_type(4))) float  f32x4;
typedef unsigned short ushort_t;

__device__ __forceinline__ ushort_t f2bf(float f) {
    unsigned u = __float_as_uint(f);
    return (ushort_t)((u + 0x7fffu + ((u >> 16) & 1u)) >> 16);
}
__device__ __forceinline__ float bflo(unsigned u) { return __uint_as_float(u << 16); }
__device__ __forceinline__ float bfhi(unsigned u) { return __uint_as_float(u & 0xffff0000u); }

// ---------------------------------------------------------------------------
// Kernel 0: pre-pack Wm/Wv into bf16 B-fragment order; zero histogram bins
// and coarse-bucket counters.
// ---------------------------------------------------------------------------
__global__ __launch_bounds__(256) void prep_w_kernel(
    const float* __restrict__ Wm, const float* __restrict__ Wv,
    ushort_t* __restrict__ fm, ushort_t* __restrict__ fv,
    int* __restrict__ gh, int* __restrict__ gcur)
{
    const int gid = blockIdx.x * 256 + threadIdx.x;   // 50176 threads
    if (gid < N_NODES) gh[gid] = 0;
    if (gid < NBKT)    gcur[gid] = 0;
    if (gid < DIN * DOUT) {
        const int k = gid >> 7, n = gid & 127;
        const int ct = n >> 4, kk = k >> 5, quad = (k >> 3) & 3, j = k & 7;
        const int idx = ((ct * 4 + kk) * 64 + quad * 16 + (n & 15)) * 8 + j;
        fm[idx] = f2bf(Wm[gid]);
        fv[idx] = f2bf(Wv[gid]);
    }
}

// ---------------------------------------------------------------------------
// Kernel 1 (FUSED): blocks [0,nH) build the dst histogram (fine 50K bins via
// global atomics + coarse 196-bin counts via LDS-privatized flush); blocks
// [nH, nH+NB_PROJ) run the MFMA projection. Data-independent; the light
// histogram role overlaps the memory-bound projection.
// ---------------------------------------------------------------------------
__global__ __launch_bounds__(256) void fused_projH_kernel(
    // proj args
    const float* __restrict__ mean, const float* __restrict__ var,
    const float* __restrict__ bm,   const float* __restrict__ bv,
    const ushort_t* __restrict__ wfm, const ushort_t* __restrict__ wfv,
    ushort_t* __restrict__ mv,
    // histogram args
    const int* __restrict__ dst, int* __restrict__ gh, int* __restrict__ gcur,
    int E, int nH)
{
    if ((int)blockIdx.x < nH) {
        // ------------------- histogram role -------------------
        __shared__ int s_h[256];
        const int t  = threadIdx.x;
        const int e0 = blockIdx.x * EPB;
        s_h[t] = 0;
        __syncthreads();
#pragma unroll
        for (int j = 0; j < 16; ++j) {
            const int e = e0 + t + j * 256;
            if (e < E) {
                const int d = dst[e];
                atomicAdd(&gh[d], 1);         // fine bin (uniform keys, low contention)
                atomicAdd(&s_h[d >> 8], 1);   // coarse bin, LDS-privatized
            }
        }
        __syncthreads();
        if (t < NBKT && s_h[t]) atomicAdd(&gcur[t], s_h[t]);
        return;
    }

    // ------------------- proj role -------------------
    const int wave = ((int)blockIdx.x - nH) * 4 + (threadIdx.x >> 6);
    if (wave >= 3125) return;
    const int lane = threadIdx.x & 63;
    const int row0 = wave * 16;
    const int kq   = lane >> 4;             // 0..3
    const int arow = row0 + (lane & 15);

    f32x4 accm[8], accv[8];
#pragma unroll
    for (int ct = 0; ct < 8; ++ct) {
        accm[ct] = (f32x4){0.f, 0.f, 0.f, 0.f};
        accv[ct] = (f32x4){0.f, 0.f, 0.f, 0.f};
    }

    const float* mrow = mean + (size_t)arow * DIN;
    const float* vrow = var  + (size_t)arow * DIN;

#pragma unroll
    for (int kk = 0; kk < 4; ++kk) {
        const int kb = kk * 32 + kq * 8;
        const float4 am0 = *(const float4*)(mrow + kb);
        const float4 am1 = *(const float4*)(mrow + kb + 4);
        const float4 av0 = *(const float4*)(vrow + kb);
        const float4 av1 = *(const float4*)(vrow + kb + 4);
        bf16x8 a_m, a_v;
        a_m[0]=f2bf(am0.x); a_m[1]=f2bf(am0.y); a_m[2]=f2bf(am0.z); a_m[3]=f2bf(am0.w);
        a_m[4]=f2bf(am1.x); a_m[5]=f2bf(am1.y); a_m[6]=f2bf(am1.z); a_m[7]=f2bf(am1.w);
        a_v[0]=f2bf(av0.x); a_v[1]=f2bf(av0.y); a_v[2]=f2bf(av0.z); a_v[3]=f2bf(av0.w);
        a_v[4]=f2bf(av1.x); a_v[5]=f2bf(av1.y); a_v[6]=f2bf(av1.z); a_v[7]=f2bf(av1.w);

#pragma unroll
        for (int ct = 0; ct < 8; ++ct) {
            const bf16x8 b_m = *(const bf16x8*)(wfm + ((size_t)(ct * 4 + kk) * 64 + lane) * 8);
            const bf16x8 b_v = *(const bf16x8*)(wfv + ((size_t)(ct * 4 + kk) * 64 + lane) * 8);
            accm[ct] = __builtin_amdgcn_mfma_f32_16x16x32_bf16(a_m, b_m, accm[ct], 0, 0, 0);
            accv[ct] = __builtin_amdgcn_mfma_f32_16x16x32_bf16(a_v, b_v, accv[ct], 0, 0, 0);
        }
    }

#pragma unroll
    for (int ct = 0; ct < 8; ++ct) {
        const int col = ct * 16 + (lane & 15);
        const float bmc = bm[col];
        const float bvc = bv[col];
        const int pbase = (col >> 1) * 4 + (col & 1);   // pair-interleave offset
#pragma unroll
        for (int r = 0; r < 4; ++r) {
            const int row = row0 + kq * 4 + r;
            float m = accm[ct][r] + bmc;
            m = (m > 0.0f) ? m : (expf(m) - 1.0f);           // ELU
            float v = accv[ct][r] + bvc;
            v = ((v > 0.0f) ? v : 0.0f) + EPS_;              // ReLU + eps
            const float att = expf(-v);
            ushort_t* rowp = mv + (size_t)row * 256;
            rowp[pbase]     = f2bf(m * att);
            rowp[pbase + 2] = f2bf(v * att * att);
        }
    }
}

// ---------------------------------------------------------------------------
// Kernel 2: CSR scan. Block b: base = sum(gcur[0..b)) via LDS reduce, then
// exclusive scan of the 256 fine bins -> node_start + cursor copy ncur.
// ---------------------------------------------------------------------------
__global__ __launch_bounds__(256) void scan_kernel(
    const int* __restrict__ gh, const int* __restrict__ gcur,
    int* __restrict__ node_start, int* __restrict__ ncur)
{
    __shared__ int s_red[256];
    __shared__ int s_scn[256];
    const int b = blockIdx.x;
    const int t = threadIdx.x;

    s_red[t] = (t < b) ? gcur[t] : 0;
    const int gidx = b * 256 + t;
    const int x = (gidx < N_NODES) ? gh[gidx] : 0;
    s_scn[t] = x;
    __syncthreads();

    for (int off = 128; off > 0; off >>= 1) {
        if (t < off) s_red[t] += s_red[t + off];
        __syncthreads();
    }
    const int base = s_red[0];

    for (int off = 1; off < 256; off <<= 1) {
        const int v = (t >= off) ? s_scn[t - off] : 0;
        __syncthreads();
        s_scn[t] += v;
        __syncthreads();
    }
    const int ns = base + s_scn[t] - x;   // exclusive prefix
    if (gidx <= N_NODES) node_start[gidx] = ns;
    if (gidx <  N_NODES) ncur[gidx] = ns;
}

// ---------------------------------------------------------------------------
// Kernel 3: scatter edges to their final dst-sorted position. Coalesced edge
// reads; 8B record scatter into final_e is L2-absorbed (every line is
// eventually fully written).
// ---------------------------------------------------------------------------
__global__ __launch_bounds__(256) void scatter_kernel(
    const int* __restrict__ src, const int* __restrict__ dst,
    const float* __restrict__ w0, const float* __restrict__ w1,
    int* __restrict__ ncur, uint2* __restrict__ final_e, int E)
{
    const int e0 = blockIdx.x * 2048 + threadIdx.x;
#pragma unroll
    for (int j = 0; j < 8; ++j) {
        const int e = e0 + j * 256;
        if (e < E) {
            const int d = dst[e];
            uint2 r;
            r.x = (unsigned)src[e];
            r.y = (unsigned)f2bf(w0[e]) | ((unsigned)f2bf(w1[e]) << 16);
            const int p = atomicAdd(&ncur[d], 1);
            final_e[p] = r;
        }
    }
}

// ---------------------------------------------------------------------------
// Kernel 4: gather aggregation — two edges per gather instruction (half-wave
// split), 16 B/lane dwordx4 from interleaved mv rows. Unchanged this round.
// ---------------------------------------------------------------------------
#define PAIR_FMA(RW, G) do {                                                 \
    const float a0 = bflo(RW), a1 = bfhi(RW);                                \
    am0 = fmaf(a0, bflo((G).x), am0); am1 = fmaf(a0, bfhi((G).x), am1);      \
    av0 = fmaf(a1, bflo((G).y), av0); av1 = fmaf(a1, bfhi((G).y), av1);      \
    am2 = fmaf(a0, bflo((G).z), am2); am3 = fmaf(a0, bfhi((G).z), am3);      \
    av2 = fmaf(a1, bflo((G).w), av2); av3 = fmaf(a1, bfhi((G).w), av3);      \
} while (0)

__global__ __launch_bounds__(256) void agg_kernel(
    const ushort_t* __restrict__ mv,
    const uint2* __restrict__ edges, const int* __restrict__ node_start,
    float* __restrict__ out_m, float* __restrict__ out_v)
{
    const int node = blockIdx.x * 4 + (threadIdx.x >> 6);
    const int lane = threadIdx.x & 63;
    const int half = lane >> 5;
    const int l    = lane & 31;
    if (node >= N_NODES) return;

    const int j0 = node_start[node];
    const int j1 = node_start[node + 1];

    float am0=0.f, am1=0.f, am2=0.f, am3=0.f;
    float av0=0.f, av1=0.f, av2=0.f, av3=0.f;

    int j = j0;

    if ((j & 1) && j < j1) {
        const uint2 r = edges[j];
        const unsigned rw = half ? 0u : r.y;
        const uint4 g = *(const uint4*)(mv + (size_t)(r.x & 0xffffu) * 256 + l * 8);
        PAIR_FMA(rw, g);
        ++j;
    }

    for (; j + 8 <= j1; j += 8) {
        const uint4 e0 = *(const uint4*)(edges + j + 0);
        const uint4 e1 = *(const uint4*)(edges + j + 2);
        const uint4 e2 = *(const uint4*)(edges + j + 4);
        const uint4 e3 = *(const uint4*)(edges + j + 6);
        const unsigned s0 = half ? e0.z : e0.x, w0 = half ? e0.w : e0.y;
        const unsigned s1 = half ? e1.z : e1.x, w1 = half ? e1.w : e1.y;
        const unsigned s2 = half ? e2.z : e2.x, w2 = half ? e2.w : e2.y;
        const unsigned s3 = half ? e3.z : e3.x, w3 = half ? e3.w : e3.y;
        const uint4 g0 = *(const uint4*)(mv + (size_t)(s0 & 0xffffu) * 256 + l * 8);
        const uint4 g1 = *(const uint4*)(mv + (size_t)(s1 & 0xffffu) * 256 + l * 8);
        const uint4 g2 = *(const uint4*)(mv + (size_t)(s2 & 0xffffu) * 256 + l * 8);
        const uint4 g3 = *(const uint4*)(mv + (size_t)(s3 & 0xffffu) * 256 + l * 8);
        PAIR_FMA(w0, g0);
        PAIR_FMA(w1, g1);
        PAIR_FMA(w2, g2);
        PAIR_FMA(w3, g3);
    }

    for (; j + 2 <= j1; j += 2) {
        const uint4 e = *(const uint4*)(edges + j);
        const unsigned s = half ? e.z : e.x, w = half ? e.w : e.y;
        const uint4 g = *(const uint4*)(mv + (size_t)(s & 0xffffu) * 256 + l * 8);
        PAIR_FMA(w, g);
    }

    if (j < j1) {
        const uint2 r = edges[j];
        const unsigned rw = half ? 0u : r.y;
        const uint4 g = *(const uint4*)(mv + (size_t)(r.x & 0xffffu) * 256 + l * 8);
        PAIR_FMA(rw, g);
    }

    am0 += __shfl_xor(am0, 32); am1 += __shfl_xor(am1, 32);
    am2 += __shfl_xor(am2, 32); am3 += __shfl_xor(am3, 32);
    av0 += __shfl_xor(av0, 32); av1 += __shfl_xor(av1, 32);
    av2 += __shfl_xor(av2, 32); av3 += __shfl_xor(av3, 32);

    if (half == 0) {
        *(float4*)(out_m + (size_t)node * DOUT + l * 4) = make_float4(am0, am1, am2, am3);
        *(float4*)(out_v + (size_t)node * DOUT + l * 4) = make_float4(av0, av1, av2, av3);
    }
}

// ---------------------------------------------------------------------------
extern "C" void kernel_launch(void* const* d_in, const int* in_sizes, int n_in,
                              void* d_out, int out_size, void* d_ws, size_t ws_size,
                              hipStream_t stream) {
    const float* mean = (const float*)d_in[0];
    const float* var  = (const float*)d_in[1];
    const float* Wm   = (const float*)d_in[2];
    const float* bm   = (const float*)d_in[3];
    const float* Wv   = (const float*)d_in[4];
    const float* bv   = (const float*)d_in[5];
    const float* a0   = (const float*)d_in[6];
    const float* a1   = (const float*)d_in[7];
    const int*   es   = (const int*)d_in[8];
    const int*   ed   = (const int*)d_in[9];
    const int    E    = in_sizes[6];

    // Workspace layout (byte offsets, 16B-aligned):
    //   mv bf16 [N][256]          0          .. 25,600,000
    //   final_e uint2[E]          25,600,000 .. 32,000,000
    //   node_start int[N+1]       32,000,000 .. 32,200,004
    //   ncur int[N]               32,200,016 .. 32,400,016
    //   gh int[N]                 32,400,032 .. 32,600,032
    //   gcur int[196]             32,600,048 .. 32,600,832
    //   wfm/wfv bf16 frags        32,600,832 .. 32,666,368
    char* ws = (char*)d_ws;
    ushort_t* mv        = (ushort_t*)ws;
    uint2* final_e      = (uint2*)(ws + 25600000);
    int*   node_start   = (int*)  (ws + 32000000);
    int*   ncur         = (int*)  (ws + 32200016);
    int*   gh           = (int*)  (ws + 32400032);
    int*   gcur         = (int*)  (ws + 32600048);
    ushort_t* wfm       = (ushort_t*)(ws + 32600832);
    ushort_t* wfv       = wfm + 16384;

    float* out_m = (float*)d_out;
    float* out_v = out_m + (size_t)N_NODES * DOUT;

    prep_w_kernel<<<(N_NODES + 255) / 256, 256, 0, stream>>>(Wm, Wv, wfm, wfv, gh, gcur);

    const int nH = (E + EPB - 1) / EPB;
    fused_projH_kernel<<<nH + NB_PROJ, 256, 0, stream>>>(
        mean, var, bm, bv, wfm, wfv, mv,
        ed, gh, gcur, E, nH);

    scan_kernel<<<NBKT, 256, 0, stream>>>(gh, gcur, node_start, ncur);

    scatter_kernel<<<(E + 2047) / 2048, 256, 0, stream>>>(
        es, ed, a0, a1, ncur, final_e, E);

    agg_kernel<<<(N_NODES + 3) / 4, 256, 0, stream>>>(
        mv, final_e, node_start, out_m, out_v);
}

// Round 2
// 211.806 us; speedup vs baseline: 1.2558x; 1.2558x over previous
//
#include <hip/hip_runtime.h>
#include <hip/hip_bf16.h>
#include <math.h>

#define N_NODES 50000
#define DIN     128
#define DOUT    128
#define EPS_    1e-6f
#define N_WAVES 3125         // N_NODES / 16 rows per wave (exact)
#define NBKT    196          // coarse buckets: dst>>8 (256 nodes each)
#define EPB     4096         // edges per bucketA block
#define SLOT_CAP 5120        // records per bucket slot (avg 4082)
#define NB_PROJ 782          // ceil(3125/4) proj blocks

typedef __attribute__((ext_vector_type(8))) short  bf16x8;
typedef __attribute__((ext_vector_type(4))) float  f32x4;
typedef __attribute__((ext_vector_type(4))) unsigned int uint4v;
typedef __attribute__((ext_vector_type(4))) float  float4v;
typedef unsigned short ushort_t;

__device__ __forceinline__ ushort_t f2bf(float f) {
    unsigned u = __float_as_uint(f);
    return (ushort_t)((u + 0x7fffu + ((u >> 16) & 1u)) >> 16);
}
__device__ __forceinline__ float bflo(unsigned u) { return __uint_as_float(u << 16); }
__device__ __forceinline__ float bfhi(unsigned u) { return __uint_as_float(u & 0xffff0000u); }

// ---------------------------------------------------------------------------
// Kernel 0: pre-pack Wm/Wv into bf16 B-fragment order; zero bucket cursors.
// ---------------------------------------------------------------------------
__global__ __launch_bounds__(256) void prep_w_kernel(
    const float* __restrict__ Wm, const float* __restrict__ Wv,
    ushort_t* __restrict__ fm, ushort_t* __restrict__ fv,
    int* __restrict__ gcur)
{
    const int gid = blockIdx.x * 256 + threadIdx.x;   // 16384 threads
    if (gid < NBKT) gcur[gid] = 0;
    const int k = gid >> 7, n = gid & 127;
    const int ct = n >> 4, kk = k >> 5, quad = (k >> 3) & 3, j = k & 7;
    const int idx = ((ct * 4 + kk) * 64 + quad * 16 + (n & 15)) * 8 + j;
    fm[idx] = f2bf(Wm[gid]);
    fv[idx] = f2bf(Wv[gid]);
}

// ---------------------------------------------------------------------------
// Kernel 1 (FUSED): blocks [0,nA) run the coarse bucket sort (phase A);
// blocks [nA, nA+NB_PROJ) run the MFMA projection. The two are data-
// independent; fusing overlaps bucketA's LDS/atomic work with proj's
// memory-bound phase and saves a dispatch.
// ---------------------------------------------------------------------------
__global__ __launch_bounds__(256) void fused_projA_kernel(
    // proj args
    const float* __restrict__ mean, const float* __restrict__ var,
    const float* __restrict__ bm,   const float* __restrict__ bv,
    const ushort_t* __restrict__ wfm, const ushort_t* __restrict__ wfv,
    ushort_t* __restrict__ mv,
    // bucketA args
    const int* __restrict__ src, const int* __restrict__ dst,
    const float* __restrict__ w0, const float* __restrict__ w1,
    int* __restrict__ gcur, uint2* __restrict__ slots, int E, int nA)
{
    if ((int)blockIdx.x < nA) {
        // ------------------- bucketA role -------------------
        __shared__ uint2 s_rec[EPB];
        __shared__ int   s_gpos[EPB];
        __shared__ int   s_hist[256];
        __shared__ int   s_scn[256];
        __shared__ int   s_cur[256];
        __shared__ int   s_base[256];

        const int t  = threadIdx.x;
        const int e0 = blockIdx.x * EPB;
        const int n  = min(EPB, E - e0);

        s_hist[t] = 0;
        __syncthreads();

        int   myb[16];
        uint2 myr[16];
#pragma unroll
        for (int j = 0; j < 16; ++j) {
            const int e = e0 + t + j * 256;
            if (e < E) {
                const int d = dst[e];
                const int b = d >> 8;
                myb[j] = b;
                myr[j].x = (unsigned)src[e] | ((unsigned)(d & 255) << 16);
                myr[j].y = (unsigned)f2bf(w0[e]) | ((unsigned)f2bf(w1[e]) << 16);
                atomicAdd(&s_hist[b], 1);
            } else myb[j] = -1;
        }
        __syncthreads();

        if (t < NBKT) {
            const int c = s_hist[t];
            s_base[t] = t * SLOT_CAP + (c ? atomicAdd(&gcur[t], c) : 0);
        }
        const int x = s_hist[t];
        s_scn[t] = x;
        __syncthreads();
        for (int off = 1; off < 256; off <<= 1) {
            const int v = (t >= off) ? s_scn[t - off] : 0;
            __syncthreads();
            s_scn[t] += v;
            __syncthreads();
        }
        const int excl = s_scn[t] - x;
        __syncthreads();
        s_scn[t] = excl;
        s_cur[t] = 0;
        __syncthreads();

#pragma unroll
        for (int j = 0; j < 16; ++j) {
            if (myb[j] >= 0) {
                const int r = atomicAdd(&s_cur[myb[j]], 1);
                const int p = s_scn[myb[j]] + r;
                s_rec[p]  = myr[j];
                s_gpos[p] = s_base[myb[j]] + r;
            }
        }
        __syncthreads();

        for (int i = t; i < n; i += 256)
            slots[s_gpos[i]] = s_rec[i];
        return;
    }

    // ------------------- proj role -------------------
    const int wave = ((int)blockIdx.x - nA) * 4 + (threadIdx.x >> 6);
    if (wave >= N_WAVES) return;
    const int lane = threadIdx.x & 63;
    const int row0 = wave * 16;
    const int kq   = lane >> 4;             // 0..3
    const int arow = row0 + (lane & 15);

    f32x4 accm[8], accv[8];
#pragma unroll
    for (int ct = 0; ct < 8; ++ct) {
        accm[ct] = (f32x4){0.f, 0.f, 0.f, 0.f};
        accv[ct] = (f32x4){0.f, 0.f, 0.f, 0.f};
    }

    const float* mrow = mean + (size_t)arow * DIN;
    const float* vrow = var  + (size_t)arow * DIN;

#pragma unroll
    for (int kk = 0; kk < 4; ++kk) {
        const int kb = kk * 32 + kq * 8;
        const float4 am0 = *(const float4*)(mrow + kb);
        const float4 am1 = *(const float4*)(mrow + kb + 4);
        const float4 av0 = *(const float4*)(vrow + kb);
        const float4 av1 = *(const float4*)(vrow + kb + 4);
        bf16x8 a_m, a_v;
        a_m[0]=f2bf(am0.x); a_m[1]=f2bf(am0.y); a_m[2]=f2bf(am0.z); a_m[3]=f2bf(am0.w);
        a_m[4]=f2bf(am1.x); a_m[5]=f2bf(am1.y); a_m[6]=f2bf(am1.z); a_m[7]=f2bf(am1.w);
        a_v[0]=f2bf(av0.x); a_v[1]=f2bf(av0.y); a_v[2]=f2bf(av0.z); a_v[3]=f2bf(av0.w);
        a_v[4]=f2bf(av1.x); a_v[5]=f2bf(av1.y); a_v[6]=f2bf(av1.z); a_v[7]=f2bf(av1.w);

#pragma unroll
        for (int ct = 0; ct < 8; ++ct) {
            const bf16x8 b_m = *(const bf16x8*)(wfm + ((size_t)(ct * 4 + kk) * 64 + lane) * 8);
            const bf16x8 b_v = *(const bf16x8*)(wfv + ((size_t)(ct * 4 + kk) * 64 + lane) * 8);
            accm[ct] = __builtin_amdgcn_mfma_f32_16x16x32_bf16(a_m, b_m, accm[ct], 0, 0, 0);
            accv[ct] = __builtin_amdgcn_mfma_f32_16x16x32_bf16(a_v, b_v, accv[ct], 0, 0, 0);
        }
    }

    // Epilogue: pack pairs of adjacent-column lanes into single dword stores.
    // Old form issued 64 scattered 2B stores/thread; this issues 32 dword
    // stores where each wave-store covers 4 fully-written 64B segments.
    const int par = lane & 1;                       // col parity == lane parity
#pragma unroll
    for (int ct = 0; ct < 8; ++ct) {
        const int col = ct * 16 + (lane & 15);
        const float bmc = bm[col];
        const float bvc = bv[col];
        const int dw = ct * 16 + ((lane & 15) >> 1) * 2 + par;  // dword idx in 128-dword row
#pragma unroll
        for (int r = 0; r < 4; ++r) {
            const int row = row0 + kq * 4 + r;
            float m = accm[ct][r] + bmc;
            m = (m > 0.0f) ? m : (expf(m) - 1.0f);           // ELU
            float v = accv[ct][r] + bvc;
            v = ((v > 0.0f) ? v : 0.0f) + EPS_;              // ReLU + eps
            const float att = expf(-v);
            const unsigned um = f2bf(m * att);
            const unsigned uv = f2bf(v * att * att);
            const unsigned om = (unsigned)__shfl_xor((int)um, 1);
            const unsigned ov = (unsigned)__shfl_xor((int)uv, 1);
            // even lane: [m(c0) | m(c1)<<16]; odd lane: [v(c0) | v(c1)<<16]
            const unsigned w = par ? (ov | (uv << 16)) : (um | (om << 16));
            ((unsigned*)(mv + (size_t)row * 256))[dw] = w;
        }
    }
}

// ---------------------------------------------------------------------------
// Kernel 2 (phase B): fine counting sort per bucket — TWO-PASS over slots
// (L2-hot). Pass 1: histogram. Pass 2: re-read + place (coalesced runs).
// ---------------------------------------------------------------------------
__global__ __launch_bounds__(256) void bucketB_kernel(
    const int* __restrict__ gcur,
    const uint2* __restrict__ slots, uint2* __restrict__ final_e,
    int* __restrict__ node_start)
{
    __shared__ int s_hist[256];
    __shared__ int s_scn[256];
    __shared__ int s_cur[256];
    __shared__ int s_red[256];

    const int b = blockIdx.x;
    const int t = threadIdx.x;

    // base = sum gcur[0..b)
    s_red[t]  = (t < b) ? gcur[t] : 0;
    s_hist[t] = 0;
    __syncthreads();
    for (int off = 128; off > 0; off >>= 1) {
        if (t < off) s_red[t] += s_red[t + off];
        __syncthreads();
    }
    const int base = s_red[0];
    const int cnt  = gcur[b];
    const uint2* slot = slots + (size_t)b * SLOT_CAP;

    // pass 1: histogram of fine key
    for (int i = t; i < cnt; i += 256)
        atomicAdd(&s_hist[(slot[i].x >> 16) & 255], 1);
    __syncthreads();

    // exclusive scan
    const int x = s_hist[t];
    s_scn[t] = x;
    __syncthreads();
    for (int off = 1; off < 256; off <<= 1) {
        const int v = (t >= off) ? s_scn[t - off] : 0;
        __syncthreads();
        s_scn[t] += v;
        __syncthreads();
    }
    const int excl = s_scn[t] - x;
    __syncthreads();

    const int gidx = b * 256 + t;
    if (gidx <= N_NODES) node_start[gidx] = base + excl;

    s_cur[t] = excl;
    __syncthreads();

    // pass 2: place records (slots re-read from L2)
    for (int i = t; i < cnt; i += 256) {
        const uint2 r = slot[i];
        const int f = (r.x >> 16) & 255;
        const int p = atomicAdd(&s_cur[f], 1);
        final_e[base + p] = r;
    }
}

// ---------------------------------------------------------------------------
// Kernel 3: gather aggregation — two edges per gather instruction (half-wave
// split), 16 B/lane dwordx4 from interleaved mv rows. This round: nontemporal
// edge loads + output stores (keep L2 dedicated to mv gathers) and a 16-edge
// unrolled block for deeper MLP.
// ---------------------------------------------------------------------------
#define PAIR_FMA(RW, G) do {                                                 \
    const float a0 = bflo(RW), a1 = bfhi(RW);                                \
    am0 = fmaf(a0, bflo((G).x), am0); am1 = fmaf(a0, bfhi((G).x), am1);      \
    av0 = fmaf(a1, bflo((G).y), av0); av1 = fmaf(a1, bfhi((G).y), av1);      \
    am2 = fmaf(a0, bflo((G).z), am2); am3 = fmaf(a0, bfhi((G).z), am3);      \
    av2 = fmaf(a1, bflo((G).w), av2); av3 = fmaf(a1, bfhi((G).w), av3);      \
} while (0)

#define EDGE_PICK(EV, S, W) \
    const unsigned S = half ? (EV).z : (EV).x, W = half ? (EV).w : (EV).y;

__global__ __launch_bounds__(256) void agg_kernel(
    const ushort_t* __restrict__ mv,
    const uint2* __restrict__ edges, const int* __restrict__ node_start,
    float* __restrict__ out_m, float* __restrict__ out_v)
{
    const int node = blockIdx.x * 4 + (threadIdx.x >> 6);
    const int lane = threadIdx.x & 63;
    const int half = lane >> 5;
    const int l    = lane & 31;
    if (node >= N_NODES) return;

    const int j0 = node_start[node];
    const int j1 = node_start[node + 1];

    float am0=0.f, am1=0.f, am2=0.f, am3=0.f;
    float av0=0.f, av1=0.f, av2=0.f, av3=0.f;

    int j = j0;

    if ((j & 1) && j < j1) {
        const uint2 r = edges[j];
        const unsigned rw = half ? 0u : r.y;
        const uint4 g = *(const uint4*)(mv + (size_t)(r.x & 0xffffu) * 256 + l * 8);
        PAIR_FMA(rw, g);
        ++j;
    }

    for (; j + 16 <= j1; j += 16) {
        const uint4v e0 = __builtin_nontemporal_load((const uint4v*)(edges + j +  0));
        const uint4v e1 = __builtin_nontemporal_load((const uint4v*)(edges + j +  2));
        const uint4v e2 = __builtin_nontemporal_load((const uint4v*)(edges + j +  4));
        const uint4v e3 = __builtin_nontemporal_load((const uint4v*)(edges + j +  6));
        const uint4v e4 = __builtin_nontemporal_load((const uint4v*)(edges + j +  8));
        const uint4v e5 = __builtin_nontemporal_load((const uint4v*)(edges + j + 10));
        const uint4v e6 = __builtin_nontemporal_load((const uint4v*)(edges + j + 12));
        const uint4v e7 = __builtin_nontemporal_load((const uint4v*)(edges + j + 14));
        EDGE_PICK(e0, s0, w0) EDGE_PICK(e1, s1, w1)
        EDGE_PICK(e2, s2, w2) EDGE_PICK(e3, s3, w3)
        EDGE_PICK(e4, s4, w4) EDGE_PICK(e5, s5, w5)
        EDGE_PICK(e6, s6, w6) EDGE_PICK(e7, s7, w7)
        const uint4 g0 = *(const uint4*)(mv + (size_t)(s0 & 0xffffu) * 256 + l * 8);
        const uint4 g1 = *(const uint4*)(mv + (size_t)(s1 & 0xffffu) * 256 + l * 8);
        const uint4 g2 = *(const uint4*)(mv + (size_t)(s2 & 0xffffu) * 256 + l * 8);
        const uint4 g3 = *(const uint4*)(mv + (size_t)(s3 & 0xffffu) * 256 + l * 8);
        const uint4 g4 = *(const uint4*)(mv + (size_t)(s4 & 0xffffu) * 256 + l * 8);
        const uint4 g5 = *(const uint4*)(mv + (size_t)(s5 & 0xffffu) * 256 + l * 8);
        const uint4 g6 = *(const uint4*)(mv + (size_t)(s6 & 0xffffu) * 256 + l * 8);
        const uint4 g7 = *(const uint4*)(mv + (size_t)(s7 & 0xffffu) * 256 + l * 8);
        PAIR_FMA(w0, g0); PAIR_FMA(w1, g1); PAIR_FMA(w2, g2); PAIR_FMA(w3, g3);
        PAIR_FMA(w4, g4); PAIR_FMA(w5, g5); PAIR_FMA(w6, g6); PAIR_FMA(w7, g7);
    }

    for (; j + 8 <= j1; j += 8) {
        const uint4v e0 = __builtin_nontemporal_load((const uint4v*)(edges + j + 0));
        const uint4v e1 = __builtin_nontemporal_load((const uint4v*)(edges + j + 2));
        const uint4v e2 = __builtin_nontemporal_load((const uint4v*)(edges + j + 4));
        const uint4v e3 = __builtin_nontemporal_load((const uint4v*)(edges + j + 6));
        EDGE_PICK(e0, s0, w0) EDGE_PICK(e1, s1, w1)
        EDGE_PICK(e2, s2, w2) EDGE_PICK(e3, s3, w3)
        const uint4 g0 = *(const uint4*)(mv + (size_t)(s0 & 0xffffu) * 256 + l * 8);
        const uint4 g1 = *(const uint4*)(mv + (size_t)(s1 & 0xffffu) * 256 + l * 8);
        const uint4 g2 = *(const uint4*)(mv + (size_t)(s2 & 0xffffu) * 256 + l * 8);
        const uint4 g3 = *(const uint4*)(mv + (size_t)(s3 & 0xffffu) * 256 + l * 8);
        PAIR_FMA(w0, g0);
        PAIR_FMA(w1, g1);
        PAIR_FMA(w2, g2);
        PAIR_FMA(w3, g3);
    }

    for (; j + 2 <= j1; j += 2) {
        const uint4v e = __builtin_nontemporal_load((const uint4v*)(edges + j));
        EDGE_PICK(e, s, w)
        const uint4 g = *(const uint4*)(mv + (size_t)(s & 0xffffu) * 256 + l * 8);
        PAIR_FMA(w, g);
    }

    if (j < j1) {
        const uint2 r = edges[j];
        const unsigned rw = half ? 0u : r.y;
        const uint4 g = *(const uint4*)(mv + (size_t)(r.x & 0xffffu) * 256 + l * 8);
        PAIR_FMA(rw, g);
    }

    am0 += __shfl_xor(am0, 32); am1 += __shfl_xor(am1, 32);
    am2 += __shfl_xor(am2, 32); am3 += __shfl_xor(am3, 32);
    av0 += __shfl_xor(av0, 32); av1 += __shfl_xor(av1, 32);
    av2 += __shfl_xor(av2, 32); av3 += __shfl_xor(av3, 32);

    if (half == 0) {
        const float4v om = {am0, am1, am2, am3};
        const float4v ov = {av0, av1, av2, av3};
        __builtin_nontemporal_store(om, (float4v*)(out_m + (size_t)node * DOUT + l * 4));
        __builtin_nontemporal_store(ov, (float4v*)(out_v + (size_t)node * DOUT + l * 4));
    }
}

// ---------------------------------------------------------------------------
extern "C" void kernel_launch(void* const* d_in, const int* in_sizes, int n_in,
                              void* d_out, int out_size, void* d_ws, size_t ws_size,
                              hipStream_t stream) {
    const float* mean = (const float*)d_in[0];
    const float* var  = (const float*)d_in[1];
    const float* Wm   = (const float*)d_in[2];
    const float* bm   = (const float*)d_in[3];
    const float* Wv   = (const float*)d_in[4];
    const float* bv   = (const float*)d_in[5];
    const float* a0   = (const float*)d_in[6];
    const float* a1   = (const float*)d_in[7];
    const int*   es   = (const int*)d_in[8];
    const int*   ed   = (const int*)d_in[9];
    const int    E    = in_sizes[6];

    // Workspace layout (byte offsets, 16B-aligned):
    //   mv [N][256] bf16           0          .. 25,600,000
    //   slots uint2[196*5120]      25,600,000 .. 33,628,160
    //   final_e uint2[E]           33,628,160 .. 40,028,160
    //   node_start int[N+1]        40,028,160 .. 40,228,164
    //   gcur int[196]              40,228,176 .. 40,228,960
    //   wfm/wfv bf16 frags         40,228,976 .. 40,294,512
    char* ws = (char*)d_ws;
    ushort_t* mv        = (ushort_t*)ws;
    uint2* slots        = (uint2*)(ws + 25600000);
    uint2* final_e      = (uint2*)(ws + 33628160);
    int*   node_start   = (int*)  (ws + 40028160);
    int*   gcur         = (int*)  (ws + 40228176);
    ushort_t* wfm       = (ushort_t*)(ws + 40228976);
    ushort_t* wfv       = wfm + 16384;

    float* out_m = (float*)d_out;
    float* out_v = out_m + (size_t)N_NODES * DOUT;

    prep_w_kernel<<<64, 256, 0, stream>>>(Wm, Wv, wfm, wfv, gcur);

    const int nA = (E + EPB - 1) / EPB;
    fused_projA_kernel<<<nA + NB_PROJ, 256, 0, stream>>>(
        mean, var, bm, bv, wfm, wfv, mv,
        es, ed, a0, a1, gcur, slots, E, nA);

    bucketB_kernel<<<NBKT, 256, 0, stream>>>(
        gcur, slots, final_e, node_start);

    agg_kernel<<<(N_NODES + 3) / 4, 256, 0, stream>>>(
        mv, final_e, node_start, out_m, out_v);
}